// Round 11
// baseline (550.178 us; speedup 1.0000x reference)
//
#include <hip/hip_runtime.h>

// B=8, S=1024, MD=1024, H=16, D=64. SCALE = (64//16)^-0.5 = 0.5.
// Inputs fp32, OUTPUTS fp32. Internal pipeline bf16 MFMA, fp32 accumulate.
// torch .view(B*H,-1,D) = flat row-major reinterpretation: attention over
// [G=128][T=1024][D=64] with flat pointer math.
//
// R10->R11: R10 proved intra-block waves are NOT TLP (shared barriers ->
// lockstep; 227us regression). Revert attn to the R9 kernel (169us best)
// with ONE change: 16 heads split across 2 INDEPENDENT blocks (hg = 8
// heads each) -> grid 512 = 2 blocks/CU (LDS 66.5KB -> 80KB granule,
// 2x80=160 fits). Co-resident blocks share no barriers -> phases truly
// interleave. attn_post = zero-fill + atomicAdd (2 commutative fp32 adds
// per address -> deterministic). GEMM reverted to R9 config (128^2, 512
// blocks, XCD N-panel swizzle) -- R10's retile was neutral.

typedef __attribute__((ext_vector_type(8))) short bf16x8;
typedef __attribute__((ext_vector_type(4))) float f32x4;

static __device__ __forceinline__ short f2bf(float f) {
  union { float f; unsigned u; } v; v.f = f;
  unsigned lsb = (v.u >> 16) & 1u;
  v.u += 0x7fffu + lsb;
  return (short)(v.u >> 16);
}

// round-half-up bf16 (2 ops); fine for positive e^x values
static __device__ __forceinline__ short f2bf_rhu(float f) {
  union { float f; unsigned u; } v; v.f = f;
  v.u += 0x8000u;
  return (short)(v.u >> 16);
}

// hardware 2^x
static __device__ __forceinline__ float exp2_hw(float x) {
  float r;
  asm("v_exp_f32 %0, %1" : "=v"(r) : "v"(x));
  return r;
}

#define L2E_HALF 0.72134752f   /* 0.5 * log2(e) : e^(score*0.5) = 2^(score*this) */

// async global->LDS, 16B per lane; LDS dest = wave-uniform base + lane*16
#define GLDS16(gp, lp) __builtin_amdgcn_global_load_lds( \
    (const __attribute__((address_space(1))) void*)(gp), \
    (__attribute__((address_space(3))) void*)(lp), 16, 0, 0)

struct Ptr4 { const float* s[4]; short* d[4]; };
struct Ptr3 { const float* s[3]; short* d[3]; };
struct QkvArgs { const short* A[3]; const short* B[3]; const float* bias[3]; short* C[3]; };

// ---------- fp32 W[k][n] -> bf16 WT[n][k], 64x64 tiles; z selects matrix ----
__global__ __launch_bounds__(256) void convt4(Ptr4 a)
{
  const float* __restrict__ src = a.s[blockIdx.z];
  short* __restrict__ dst = a.d[blockIdx.z];
  __shared__ float T[64][65];
  const int tid = threadIdx.x;
  const int c0 = blockIdx.x * 64, r0 = blockIdx.y * 64;
  {
    const int rr = tid >> 4, cc = (tid & 15) * 4;
    for (int i = 0; i < 4; ++i) {
      int row = rr + i * 16;
      const float4 v = *(const float4*)(src + (size_t)(r0 + row) * 1024 + c0 + cc);
      T[row][cc] = v.x; T[row][cc + 1] = v.y; T[row][cc + 2] = v.z; T[row][cc + 3] = v.w;
    }
  }
  __syncthreads();
  {
    const int rr = tid >> 3, cc = (tid & 7) * 8;
    for (int i = 0; i < 2; ++i) {
      int row = rr + i * 32;             // dst row within tile (= src col)
      bf16x8 v;
      for (int j = 0; j < 8; ++j) v[j] = f2bf(T[cc + j][row]);
      *(bf16x8*)(dst + (size_t)(c0 + row) * 1024 + r0 + cc) = v;
    }
  }
}

// ---------- fp32 -> bf16 elementwise; z selects tensor ----------
__global__ __launch_bounds__(256) void cvt3(Ptr3 a)
{
  const float* __restrict__ src = a.s[blockIdx.z];
  short* __restrict__ dst = a.d[blockIdx.z];
  const size_t i = ((size_t)blockIdx.x * 256 + threadIdx.x) * 8;
  const float4 v0 = *(const float4*)(src + i);
  const float4 v1 = *(const float4*)(src + i + 4);
  bf16x8 o;
  o[0] = f2bf(v0.x); o[1] = f2bf(v0.y); o[2] = f2bf(v0.z); o[3] = f2bf(v0.w);
  o[4] = f2bf(v1.x); o[5] = f2bf(v1.y); o[6] = f2bf(v1.z); o[7] = f2bf(v1.w);
  *(bf16x8*)(dst + i) = o;
}

// ---------- zero fill fp32 (for attn_post atomic accumulation) ----------
// grid 2048: 2048*256*16 = 8M floats exactly.
__global__ __launch_bounds__(256) void zero_f32(float* __restrict__ p)
{
  const size_t i = ((size_t)blockIdx.x * 256 + threadIdx.x) * 16;
  const float4 z = {0.f, 0.f, 0.f, 0.f};
  *(float4*)(p + i) = z; *(float4*)(p + i + 4) = z;
  *(float4*)(p + i + 8) = z; *(float4*)(p + i + 12) = z;
}

// ---------- per-g 64x64 bf16 tile transpose: V[g][t][d] -> VpT[g][d][t] ----
__global__ __launch_bounds__(256) void transp_v(
    const short* __restrict__ src, short* __restrict__ dst)
{
  __shared__ short T[64][72];
  const int g = blockIdx.y, t0 = blockIdx.x * 64;
  const short* s = src + (size_t)g * 65536 + (size_t)t0 * 64;
  short* d = dst + (size_t)g * 65536 + t0;
  const int r = threadIdx.x >> 3, c = (threadIdx.x & 7) * 8;
  for (int i = 0; i < 2; ++i) {
    bf16x8 v = *(const bf16x8*)(s + (size_t)(r + i * 32) * 64 + c);
    *(bf16x8*)(&T[r + i * 32][c]) = v;
  }
  __syncthreads();
  for (int i = 0; i < 2; ++i) {
    int dr = r + i * 32;                 // d index
    bf16x8 v;
    for (int j = 0; j < 8; ++j) v[j] = T[c + j][dr];
    *(bf16x8*)(d + (size_t)dr * 1024 + c) = v;
  }
}

// ---------- GEMM body: C[8192,1024] = A[8192,1024](bf16) * BT[1024,1024]^T + bias
// R9 config: 128x128 tiles, 512 blocks; XCD swizzle: lin%8 = hw XCD = by
// (N-panel per XCD, 256KB B L2-resident); bx = (lin>>3)&63. Bijective.
static __device__ __forceinline__ void gemm_body(
    const short* __restrict__ A, const short* __restrict__ BT,
    const float* __restrict__ bias, void* __restrict__ Cp, int mode)
{
  __shared__ short As[128 * 64];
  __shared__ short Bs[128 * 64];
  const int K = 1024, N = 1024;
  const int tid = threadIdx.x;
  const int lane = tid & 63, wave = tid >> 6;
  const int quad = lane >> 4, l16 = lane & 15;
  const int wm = (wave & 1) * 64, wn = (wave >> 1) * 64;
  const int lin = blockIdx.y * 64 + blockIdx.x;
  const int bx = (lin >> 3) & 63;        // 0..63 M-tile
  const int by = lin & 7;                // 0..7  N-tile == XCD id
  const int bm = bx * 128, bn = by * 128;

  f32x4 acc[4][4] = {};

  const int s_row = tid >> 3;            // 0..31
  const int s_col = (tid & 7) * 8;       // 0..56 (shorts)
  const int lds_base = wave * 512;       // wave-uniform (shorts)

  for (int k0 = 0; k0 < K; k0 += 64) {
    for (int i = 0; i < 4; ++i) {
      int row = s_row + i * 32;
      GLDS16(A + (size_t)(bm + row) * K + k0 + s_col, &As[i * 2048 + lds_base]);
      GLDS16(BT + (size_t)(bn + row) * K + k0 + s_col, &Bs[i * 2048 + lds_base]);
    }
    __syncthreads();
    for (int ks = 0; ks < 2; ++ks) {
      bf16x8 af[4], bfr[4];
      for (int mi = 0; mi < 4; ++mi)
        af[mi] = *(const bf16x8*)(&As[(wm + mi * 16 + l16) * 64 + ks * 32 + quad * 8]);
      for (int ni = 0; ni < 4; ++ni)
        bfr[ni] = *(const bf16x8*)(&Bs[(wn + ni * 16 + l16) * 64 + ks * 32 + quad * 8]);
      for (int mi = 0; mi < 4; ++mi)
        for (int ni = 0; ni < 4; ++ni)
          acc[mi][ni] = __builtin_amdgcn_mfma_f32_16x16x32_bf16(af[mi], bfr[ni], acc[mi][ni], 0, 0, 0);
    }
    __syncthreads();
  }

  for (int ni = 0; ni < 4; ++ni) {
    int col = bn + wn + ni * 16 + l16;
    float bv = bias[col];
    for (int mi = 0; mi < 4; ++mi) {
      int row0 = bm + wm + mi * 16 + quad * 4;   // C row = quad*4+reg
      for (int r = 0; r < 4; ++r) {
        int row = row0 + r;
        float fv = acc[mi][ni][r] + bv;
        if (mode == 2) ((float*)Cp)[(size_t)row * N + col] = fv;
        else           ((short*)Cp)[(size_t)row * N + col] = f2bf(fv);
      }
    }
  }
}

__global__ __launch_bounds__(256) void gemm_bt16(
    const short* __restrict__ A, const short* __restrict__ BT,
    const float* __restrict__ bias, void* __restrict__ Cp, int mode)
{
  gemm_body(A, BT, bias, Cp, mode);
}

// combined Q/K/V projection: grid.z selects which GEMM
__global__ __launch_bounds__(256) void gemm_qkv(QkvArgs a)
{
  const int z = blockIdx.z;
  gemm_body(a.A[z], a.B[z], a.bias[z], a.C[z], 0);
}

// ---------- fused attention over [G=128,T=1024,D=64] ----------
// R9 kernel verbatim except head-group split: block = (b, hg of 8 heads,
// 32-row t-tile); grid 512 = 2 INDEPENDENT blocks/CU (no shared barriers
// -> phases interleave across blocks). 256 thr / 4 waves; score s-strips
// of 256; each K fragment pair feeds 2 t-tiles. Raw e^x -> Plds (deferred
// normalization); sig[2][16][4] regs. B1. PV: R9's verified d-split (wave
// owns 16 d-cols, full s=1024). attn_post: atomicAdd (pre-zeroed; 2
// commutative fp32 adds per address = deterministic).
__global__ __launch_bounds__(256, 2) void attn_fused10(
    const short* __restrict__ Qp, const short* __restrict__ Kp,
    const short* __restrict__ VpT,               // [g][d][t]
    short* __restrict__ ctx,                     // [g][t][d] flat (bf16)
    float* __restrict__ attn_post)               // [b][t][s] FP32, atomic
{
  __shared__ short Plds[32][1032];               // 66KB
  __shared__ float red[32][4];

  const int tid = threadIdx.x;
  const int wave = tid >> 6, lane = tid & 63;
  const int quad = lane >> 4, l16 = lane & 15;
  // XCD-chunk remap (T1): b == orig&7  (XCD i <- batch i)
  const int orig = blockIdx.x;                   // 0..511
  const int b = orig & 7;
  const int hg = (orig >> 3) & 1;                // head group (8 heads)
  const int t0 = (orig >> 4) * 32;               // 32-row t-tile
  const int sbase = wave * 256;

  float sig[2][16][4] = {};                      // [tt][tile][r], 8-head sum

  for (int h = hg * 8; h < hg * 8 + 8; ++h) {
    const int g = b * 16 + h;
    const short* Qg = Qp + (size_t)g * 65536;
    const short* Kg = Kp + (size_t)g * 65536;
    const short* Vg = VpT + (size_t)g * 65536;

    bf16x8 aq[2][2];
#pragma unroll
    for (int tt = 0; tt < 2; ++tt) {
      aq[tt][0] = *(const bf16x8*)(Qg + (t0 + tt * 16 + l16) * 64 + quad * 8);
      aq[tt][1] = *(const bf16x8*)(Qg + (t0 + tt * 16 + l16) * 64 + 32 + quad * 8);
    }

    float rsum[2][4] = {};

    // ---- QK^T score loop: 16 s-tiles, K prefetched 4 tiles deep ----
    bf16x8 kb0[4], kb1[4];
#pragma unroll
    for (int t = 0; t < 4; ++t) {
      int s = sbase + t * 16;
      kb0[t] = *(const bf16x8*)(Kg + (s + l16) * 64 + quad * 8);
      kb1[t] = *(const bf16x8*)(Kg + (s + l16) * 64 + 32 + quad * 8);
    }
#pragma unroll
    for (int tile = 0; tile < 16; ++tile) {
      const int slot = tile & 3;
      bf16x8 bk0 = kb0[slot], bk1 = kb1[slot];
      if (tile < 12) {
        int s = sbase + (tile + 4) * 16;
        kb0[slot] = *(const bf16x8*)(Kg + (s + l16) * 64 + quad * 8);
        kb1[slot] = *(const bf16x8*)(Kg + (s + l16) * 64 + 32 + quad * 8);
      }
#pragma unroll
      for (int tt = 0; tt < 2; ++tt) {
        f32x4 c = {0.f, 0.f, 0.f, 0.f};
        c = __builtin_amdgcn_mfma_f32_16x16x32_bf16(aq[tt][0], bk0, c, 0, 0, 0);
        c = __builtin_amdgcn_mfma_f32_16x16x32_bf16(aq[tt][1], bk1, c, 0, 0, 0);
#pragma unroll
        for (int r = 0; r < 4; ++r) {
          float e = exp2_hw(c[r] * L2E_HALF);    // e^(score*0.5)
          rsum[tt][r] += e;
          Plds[tt * 16 + quad * 4 + r][sbase + tile * 16 + l16] = f2bf_rhu(e);
          sig[tt][tile][r] += e * __builtin_amdgcn_rcpf(1.f + e);   // sigmoid
        }
      }
    }
#pragma unroll
    for (int tt = 0; tt < 2; ++tt)
      for (int r = 0; r < 4; ++r)
        for (int mask = 1; mask < 16; mask <<= 1)
          rsum[tt][r] += __shfl_xor(rsum[tt][r], mask, 64);
    if (l16 == 0)
#pragma unroll
      for (int tt = 0; tt < 2; ++tt)
        for (int r = 0; r < 4; ++r)
          red[tt * 16 + quad * 4 + r][wave] = rsum[tt][r];
    __syncthreads();                             // B1: Plds + red visible

    // ---- PV: wave owns d-cols [wave*16, wave*16+16), full s=1024 ----
    // A = P[t-within-tile = l16][s-slice], B = V^T[d = wave*16+l16][s-slice].
    const short* Vw = Vg + (size_t)(wave * 16 + l16) * 1024;
    f32x4 acc[2][2] = {};                        // [tt][parity]
#pragma unroll
    for (int sl = 0; sl < 32; ++sl) {
      bf16x8 v  = *(const bf16x8*)(Vw + sl * 32 + quad * 8);
      bf16x8 p0 = *(const bf16x8*)(&Plds[l16][sl * 32 + quad * 8]);
      bf16x8 p1 = *(const bf16x8*)(&Plds[16 + l16][sl * 32 + quad * 8]);
      acc[0][sl & 1] = __builtin_amdgcn_mfma_f32_16x16x32_bf16(p0, v, acc[0][sl & 1], 0, 0, 0);
      acc[1][sl & 1] = __builtin_amdgcn_mfma_f32_16x16x32_bf16(p1, v, acc[1][sl & 1], 0, 0, 0);
    }

    // normalize by 1/rowsum and write ctx directly
    short* ctxg = ctx + (size_t)g * 65536 + t0 * 64;
#pragma unroll
    for (int tt = 0; tt < 2; ++tt)
      for (int r = 0; r < 4; ++r) {
        int row = tt * 16 + quad * 4 + r;
        float s4 = red[row][0] + red[row][1] + red[row][2] + red[row][3];
        float inv = __builtin_amdgcn_rcpf(s4);
        float cval = (acc[tt][0][r] + acc[tt][1][r]) * inv;
        ctxg[row * 64 + wave * 16 + l16] = f2bf(cval);
      }
    __syncthreads();                             // B2: Plds/red free for next head
  }

  float* ap_out = attn_post + (size_t)b * 1048576 + (size_t)t0 * 1024;
#pragma unroll
  for (int tt = 0; tt < 2; ++tt)
    for (int tile = 0; tile < 16; ++tile)
      for (int r = 0; r < 4; ++r)
        atomicAdd(&ap_out[(tt * 16 + quad * 4 + r) * 1024 + sbase + tile * 16 + l16],
                  sig[tt][tile][r] * 0.0625f);
}

extern "C" void kernel_launch(void* const* d_in, const int* in_sizes, int n_in,
                              void* d_out, int out_size, void* d_ws, size_t ws_size,
                              hipStream_t stream) {
  const float* query = (const float*)d_in[0];
  const float* key   = (const float*)d_in[1];
  const float* value = (const float*)d_in[2];
  const float* Wq = (const float*)d_in[3]; const float* bq = (const float*)d_in[4];
  const float* Wk = (const float*)d_in[5]; const float* bk = (const float*)d_in[6];
  const float* Wv = (const float*)d_in[7]; const float* bv = (const float*)d_in[8];
  const float* Wo = (const float*)d_in[9]; const float* bo = (const float*)d_in[10];

  float* out0 = (float*)d_out;              // [8,1024,1024] fp32
  float* attn_post = out0 + (8u << 20);     // [8,1024,1024] fp32

  // common workspace head: 4 x 1M weightT + 3 x 8M (Qp,Kp,VpT)
  short* WqT = (short*)d_ws;
  short* WkT = WqT + (1u << 20);
  short* WvT = WkT + (1u << 20);
  short* WoT = WvT + (1u << 20);
  short* Qp  = WoT + (1u << 20);
  short* Kp  = Qp + (8u << 20);
  short* VpT = Kp + (8u << 20);

  dim3 blk(256);
  dim3 ggrid(64, 8);                        // 512 blocks, 128x128 tiles
  const size_t NEED_BIG = (size_t)(60u << 20) * 2;   // 120 MiB

  convt4<<<dim3(16, 16, 4), blk, 0, stream>>>(
      Ptr4{{Wq, Wk, Wv, Wo}, {WqT, WkT, WvT, WoT}});
  zero_f32<<<dim3(2048), blk, 0, stream>>>(attn_post);

  short* ctx;
  if (ws_size >= NEED_BIG) {
    // big layout: + Xq,Xk,Xv (3 x 8M) + Vflat (8M) = 60M shorts total
    short* Xq = VpT + (8u << 20);
    short* Xk = Xq + (8u << 20);
    short* Xv = Xk + (8u << 20);
    short* Vflat = Xv + (8u << 20);
    ctx = Xq;                                      // dead after qkv GEMM

    cvt3<<<dim3(4096, 1, 3), blk, 0, stream>>>(Ptr3{{query, key, value}, {Xq, Xk, Xv}});
    gemm_qkv<<<dim3(64, 8, 3), blk, 0, stream>>>(
        QkvArgs{{Xq, Xk, Xv}, {WqT, WkT, WvT}, {bq, bk, bv}, {Qp, Kp, Vflat}});
    transp_v<<<dim3(16, 128), blk, 0, stream>>>(Vflat, VpT);
  } else {
    // small layout (88 MB, proven): Xin (8M) + Vflat (8M), sequential
    short* Xin = VpT + (8u << 20);
    short* Vflat = Xin + (8u << 20);
    ctx = Xin;

    cvt3<<<dim3(4096, 1, 1), blk, 0, stream>>>(Ptr3{{query, query, query}, {Xin, Xin, Xin}});
    gemm_bt16<<<ggrid, blk, 0, stream>>>(Xin, WqT, bq, Qp, 0);
    cvt3<<<dim3(4096, 1, 1), blk, 0, stream>>>(Ptr3{{key, key, key}, {Xin, Xin, Xin}});
    gemm_bt16<<<ggrid, blk, 0, stream>>>(Xin, WkT, bk, Kp, 0);
    cvt3<<<dim3(4096, 1, 1), blk, 0, stream>>>(Ptr3{{value, value, value}, {Xin, Xin, Xin}});
    gemm_bt16<<<ggrid, blk, 0, stream>>>(Xin, WvT, bv, Vflat, 0);
    transp_v<<<dim3(16, 128), blk, 0, stream>>>(Vflat, VpT);
  }

  attn_fused10<<<dim3(512), blk, 0, stream>>>(Qp, Kp, VpT, ctx, attn_post);
  gemm_bt16<<<ggrid, blk, 0, stream>>>(ctx, WoT, bo, out0, 2);
}

// Round 12
// 454.386 us; speedup vs baseline: 1.2108x; 1.2108x over previous
//
#include <hip/hip_runtime.h>

// B=8, S=1024, MD=1024, H=16, D=64. SCALE = (64//16)^-0.5 = 0.5.
// Inputs fp32, OUTPUTS fp32. Internal pipeline bf16 MFMA, fp32 accumulate.
// torch .view(B*H,-1,D) = flat row-major reinterpretation: attention over
// [G=128][T=1024][D=64] with flat pointer math.
//
// R11->R12: R11's regression was atomic-RMW L2 poisoning (FETCH 197MB,
// WRITE 334MB), and R5 already falsified occupancy/TLP as the attn lever.
// attn restored to R9 verbatim (169.5us, demonstrated floor). GEMM (never
// improved, ~57us each) gets two fixes: (1) M-panel XCD swizzle -- XCD i
// owns M-tiles [8i,8i+8) so A-panel (2MB) AND B (2MB) are L2-resident
// (old N-panel map streamed all of A through every XCD, ~144MB/GEMM);
// (2) T3-min 2-phase pipeline: double-buffered LDS, stage tile t+1 BEFORE
// computing tile t, ONE barrier per k-step -- the compiler's vmcnt(0)
// drain now lands after the MFMAs, hiding load latency under compute
// (old order stage->barrier->compute had zero overlap by construction).

typedef __attribute__((ext_vector_type(8))) short bf16x8;
typedef __attribute__((ext_vector_type(4))) float f32x4;

static __device__ __forceinline__ short f2bf(float f) {
  union { float f; unsigned u; } v; v.f = f;
  unsigned lsb = (v.u >> 16) & 1u;
  v.u += 0x7fffu + lsb;
  return (short)(v.u >> 16);
}

// round-half-up bf16 (2 ops); fine for positive e^x values
static __device__ __forceinline__ short f2bf_rhu(float f) {
  union { float f; unsigned u; } v; v.f = f;
  v.u += 0x8000u;
  return (short)(v.u >> 16);
}

// hardware 2^x
static __device__ __forceinline__ float exp2_hw(float x) {
  float r;
  asm("v_exp_f32 %0, %1" : "=v"(r) : "v"(x));
  return r;
}

#define L2E_HALF 0.72134752f   /* 0.5 * log2(e) : e^(score*0.5) = 2^(score*this) */

// async global->LDS, 16B per lane; LDS dest = wave-uniform base + lane*16
#define GLDS16(gp, lp) __builtin_amdgcn_global_load_lds( \
    (const __attribute__((address_space(1))) void*)(gp), \
    (__attribute__((address_space(3))) void*)(lp), 16, 0, 0)

struct Ptr4 { const float* s[4]; short* d[4]; };
struct Ptr3 { const float* s[3]; short* d[3]; };
struct QkvArgs { const short* A[3]; const short* B[3]; const float* bias[3]; short* C[3]; };

// ---------- fp32 W[k][n] -> bf16 WT[n][k], 64x64 tiles; z selects matrix ----
__global__ __launch_bounds__(256) void convt4(Ptr4 a)
{
  const float* __restrict__ src = a.s[blockIdx.z];
  short* __restrict__ dst = a.d[blockIdx.z];
  __shared__ float T[64][65];
  const int tid = threadIdx.x;
  const int c0 = blockIdx.x * 64, r0 = blockIdx.y * 64;
  {
    const int rr = tid >> 4, cc = (tid & 15) * 4;
    for (int i = 0; i < 4; ++i) {
      int row = rr + i * 16;
      const float4 v = *(const float4*)(src + (size_t)(r0 + row) * 1024 + c0 + cc);
      T[row][cc] = v.x; T[row][cc + 1] = v.y; T[row][cc + 2] = v.z; T[row][cc + 3] = v.w;
    }
  }
  __syncthreads();
  {
    const int rr = tid >> 3, cc = (tid & 7) * 8;
    for (int i = 0; i < 2; ++i) {
      int row = rr + i * 32;             // dst row within tile (= src col)
      bf16x8 v;
      for (int j = 0; j < 8; ++j) v[j] = f2bf(T[cc + j][row]);
      *(bf16x8*)(dst + (size_t)(c0 + row) * 1024 + r0 + cc) = v;
    }
  }
}

// ---------- fp32 -> bf16 elementwise; z selects tensor ----------
__global__ __launch_bounds__(256) void cvt3(Ptr3 a)
{
  const float* __restrict__ src = a.s[blockIdx.z];
  short* __restrict__ dst = a.d[blockIdx.z];
  const size_t i = ((size_t)blockIdx.x * 256 + threadIdx.x) * 8;
  const float4 v0 = *(const float4*)(src + i);
  const float4 v1 = *(const float4*)(src + i + 4);
  bf16x8 o;
  o[0] = f2bf(v0.x); o[1] = f2bf(v0.y); o[2] = f2bf(v0.z); o[3] = f2bf(v0.w);
  o[4] = f2bf(v1.x); o[5] = f2bf(v1.y); o[6] = f2bf(v1.z); o[7] = f2bf(v1.w);
  *(bf16x8*)(dst + i) = o;
}

// ---------- per-g 64x64 bf16 tile transpose: V[g][t][d] -> VpT[g][d][t] ----
__global__ __launch_bounds__(256) void transp_v(
    const short* __restrict__ src, short* __restrict__ dst)
{
  __shared__ short T[64][72];
  const int g = blockIdx.y, t0 = blockIdx.x * 64;
  const short* s = src + (size_t)g * 65536 + (size_t)t0 * 64;
  short* d = dst + (size_t)g * 65536 + t0;
  const int r = threadIdx.x >> 3, c = (threadIdx.x & 7) * 8;
  for (int i = 0; i < 2; ++i) {
    bf16x8 v = *(const bf16x8*)(s + (size_t)(r + i * 32) * 64 + c);
    *(bf16x8*)(&T[r + i * 32][c]) = v;
  }
  __syncthreads();
  for (int i = 0; i < 2; ++i) {
    int dr = r + i * 32;                 // d index
    bf16x8 v;
    for (int j = 0; j < 8; ++j) v[j] = T[c + j][dr];
    *(bf16x8*)(d + (size_t)dr * 1024 + c) = v;
  }
}

// ---------- GEMM body: C[8192,1024] = A[8192,1024](bf16) * BT[1024,1024]^T + bias
// 128x128 tiles, 512 blocks. M-panel XCD swizzle: xcd = lin&7 owns M-tiles
// [8*xcd, 8*xcd+8) x all 8 N-tiles -> A-panel (2MB) + B (2MB) L2-resident
// per XCD. Bijective. 2-phase pipeline: dbuf LDS, stage t+1 before compute
// of t, one barrier per k-step (vmcnt drain lands after MFMAs).
static __device__ __forceinline__ void gemm_body(
    const short* __restrict__ A, const short* __restrict__ BT,
    const float* __restrict__ bias, void* __restrict__ Cp, int mode)
{
  __shared__ short As[2][128 * 64];
  __shared__ short Bs[2][128 * 64];
  const int K = 1024, N = 1024;
  const int tid = threadIdx.x;
  const int lane = tid & 63, wave = tid >> 6;
  const int quad = lane >> 4, l16 = lane & 15;
  const int wm = (wave & 1) * 64, wn = (wave >> 1) * 64;
  const int lin = blockIdx.y * 64 + blockIdx.x;
  const int xcd = lin & 7, idx = lin >> 3;       // idx 0..63
  const int bx = xcd * 8 + (idx & 7);            // M-tile 0..63
  const int by = idx >> 3;                       // N-tile 0..7
  const int bm = bx * 128, bn = by * 128;

  f32x4 acc[4][4] = {};

  const int s_row = tid >> 3;            // 0..31
  const int s_col = (tid & 7) * 8;       // 0..56 (shorts)
  const int lds_base = wave * 512;       // wave-uniform (shorts)

  // prologue: stage k0=0 into buffer 0
  for (int i = 0; i < 4; ++i) {
    int row = s_row + i * 32;
    GLDS16(A + (size_t)(bm + row) * K + s_col, &As[0][i * 2048 + lds_base]);
    GLDS16(BT + (size_t)(bn + row) * K + s_col, &Bs[0][i * 2048 + lds_base]);
  }
  __syncthreads();                       // drains prologue stage

  int cur = 0;
  for (int t = 0; t < 16; ++t) {
    // stage NEXT k-tile first (loads fly during compute below)
    if (t < 15) {
      const int k0 = (t + 1) * 64;
      for (int i = 0; i < 4; ++i) {
        int row = s_row + i * 32;
        GLDS16(A + (size_t)(bm + row) * K + k0 + s_col, &As[cur ^ 1][i * 2048 + lds_base]);
        GLDS16(BT + (size_t)(bn + row) * K + k0 + s_col, &Bs[cur ^ 1][i * 2048 + lds_base]);
      }
    }
    // compute current tile
    for (int ks = 0; ks < 2; ++ks) {
      bf16x8 af[4], bfr[4];
      for (int mi = 0; mi < 4; ++mi)
        af[mi] = *(const bf16x8*)(&As[cur][(wm + mi * 16 + l16) * 64 + ks * 32 + quad * 8]);
      for (int ni = 0; ni < 4; ++ni)
        bfr[ni] = *(const bf16x8*)(&Bs[cur][(wn + ni * 16 + l16) * 64 + ks * 32 + quad * 8]);
      for (int mi = 0; mi < 4; ++mi)
        for (int ni = 0; ni < 4; ++ni)
          acc[mi][ni] = __builtin_amdgcn_mfma_f32_16x16x32_bf16(af[mi], bfr[ni], acc[mi][ni], 0, 0, 0);
    }
    __syncthreads();                     // drains next-tile stage; guards buffer reuse
    cur ^= 1;
  }

  for (int ni = 0; ni < 4; ++ni) {
    int col = bn + wn + ni * 16 + l16;
    float bv = bias[col];
    for (int mi = 0; mi < 4; ++mi) {
      int row0 = bm + wm + mi * 16 + quad * 4;   // C row = quad*4+reg
      for (int r = 0; r < 4; ++r) {
        int row = row0 + r;
        float fv = acc[mi][ni][r] + bv;
        if (mode == 2) ((float*)Cp)[(size_t)row * N + col] = fv;
        else           ((short*)Cp)[(size_t)row * N + col] = f2bf(fv);
      }
    }
  }
}

__global__ __launch_bounds__(256) void gemm_bt16(
    const short* __restrict__ A, const short* __restrict__ BT,
    const float* __restrict__ bias, void* __restrict__ Cp, int mode)
{
  gemm_body(A, BT, bias, Cp, mode);
}

// combined Q/K/V projection: grid.z selects which GEMM
__global__ __launch_bounds__(256) void gemm_qkv(QkvArgs a)
{
  const int z = blockIdx.z;
  gemm_body(a.A[z], a.B[z], a.bias[z], a.C[z], 0);
}

// ---------- fused attention over [G=128,T=1024,D=64] (R9 verbatim) ----------
// block = (b via XCD remap, 32-row t-tile); grid 256 = 1 block/CU.
// Score: 4 waves x s=256 strips; each K fragment pair feeds 2 t-tiles
// (4 MFMA). Raw e^x -> Plds (deferred normalization); sig in regs.
// B1. PV: d-split, wave owns 16 d-cols, full s=1024, V fragment shared by
// both t-tiles; scale by 1/rowsum from red; ctx written straight to
// global. B2 guards Plds reuse.
__global__ __launch_bounds__(256, 1) void attn_fused8(
    const short* __restrict__ Qp, const short* __restrict__ Kp,
    const short* __restrict__ VpT,               // [g][d][t]
    short* __restrict__ ctx,                     // [g][t][d] flat (bf16)
    float* __restrict__ attn_post)               // [b][t][s] FP32
{
  __shared__ short Plds[32][1032];               // 66KB
  __shared__ float red[32][4];

  const int tid = threadIdx.x;
  const int wave = tid >> 6, lane = tid & 63;
  const int quad = lane >> 4, l16 = lane & 15;
  // XCD-chunk remap (T1): b == orig&7  (XCD i <- batch i)
  const int orig = blockIdx.x;                   // 0..255
  const int b = orig & 7;
  const int t0 = (orig >> 3) * 32;               // 32-row t-tile
  const int sbase = wave * 256;

  float sig[2][16][4] = {};                      // [tt][tile][r]

  for (int h = 0; h < 16; ++h) {
    const int g = b * 16 + h;
    const short* Qg = Qp + (size_t)g * 65536;
    const short* Kg = Kp + (size_t)g * 65536;
    const short* Vg = VpT + (size_t)g * 65536;

    bf16x8 aq[2][2];
#pragma unroll
    for (int tt = 0; tt < 2; ++tt) {
      aq[tt][0] = *(const bf16x8*)(Qg + (t0 + tt * 16 + l16) * 64 + quad * 8);
      aq[tt][1] = *(const bf16x8*)(Qg + (t0 + tt * 16 + l16) * 64 + 32 + quad * 8);
    }

    float rsum[2][4] = {};

    // ---- QK^T score loop: 16 s-tiles, K prefetched 4 tiles deep ----
    bf16x8 kb0[4], kb1[4];
#pragma unroll
    for (int t = 0; t < 4; ++t) {
      int s = sbase + t * 16;
      kb0[t] = *(const bf16x8*)(Kg + (s + l16) * 64 + quad * 8);
      kb1[t] = *(const bf16x8*)(Kg + (s + l16) * 64 + 32 + quad * 8);
    }
#pragma unroll
    for (int tile = 0; tile < 16; ++tile) {
      const int slot = tile & 3;
      bf16x8 bk0 = kb0[slot], bk1 = kb1[slot];
      if (tile < 12) {
        int s = sbase + (tile + 4) * 16;
        kb0[slot] = *(const bf16x8*)(Kg + (s + l16) * 64 + quad * 8);
        kb1[slot] = *(const bf16x8*)(Kg + (s + l16) * 64 + 32 + quad * 8);
      }
#pragma unroll
      for (int tt = 0; tt < 2; ++tt) {
        f32x4 c = {0.f, 0.f, 0.f, 0.f};
        c = __builtin_amdgcn_mfma_f32_16x16x32_bf16(aq[tt][0], bk0, c, 0, 0, 0);
        c = __builtin_amdgcn_mfma_f32_16x16x32_bf16(aq[tt][1], bk1, c, 0, 0, 0);
#pragma unroll
        for (int r = 0; r < 4; ++r) {
          float e = exp2_hw(c[r] * L2E_HALF);    // e^(score*0.5)
          rsum[tt][r] += e;
          Plds[tt * 16 + quad * 4 + r][sbase + tile * 16 + l16] = f2bf_rhu(e);
          sig[tt][tile][r] += e * __builtin_amdgcn_rcpf(1.f + e);   // sigmoid
        }
      }
    }
#pragma unroll
    for (int tt = 0; tt < 2; ++tt)
      for (int r = 0; r < 4; ++r)
        for (int mask = 1; mask < 16; mask <<= 1)
          rsum[tt][r] += __shfl_xor(rsum[tt][r], mask, 64);
    if (l16 == 0)
#pragma unroll
      for (int tt = 0; tt < 2; ++tt)
        for (int r = 0; r < 4; ++r)
          red[tt * 16 + quad * 4 + r][wave] = rsum[tt][r];
    __syncthreads();                             // B1: Plds + red visible

    // ---- PV: wave owns d-cols [wave*16, wave*16+16), full s=1024 ----
    // A = P[t-within-tile = l16][s-slice], B = V^T[d = wave*16+l16][s-slice].
    const short* Vw = Vg + (size_t)(wave * 16 + l16) * 1024;
    f32x4 acc[2][2] = {};                        // [tt][parity]
#pragma unroll
    for (int sl = 0; sl < 32; ++sl) {
      bf16x8 v  = *(const bf16x8*)(Vw + sl * 32 + quad * 8);
      bf16x8 p0 = *(const bf16x8*)(&Plds[l16][sl * 32 + quad * 8]);
      bf16x8 p1 = *(const bf16x8*)(&Plds[16 + l16][sl * 32 + quad * 8]);
      acc[0][sl & 1] = __builtin_amdgcn_mfma_f32_16x16x32_bf16(p0, v, acc[0][sl & 1], 0, 0, 0);
      acc[1][sl & 1] = __builtin_amdgcn_mfma_f32_16x16x32_bf16(p1, v, acc[1][sl & 1], 0, 0, 0);
    }

    // normalize by 1/rowsum and write ctx directly
    short* ctxg = ctx + (size_t)g * 65536 + t0 * 64;
#pragma unroll
    for (int tt = 0; tt < 2; ++tt)
      for (int r = 0; r < 4; ++r) {
        int row = tt * 16 + quad * 4 + r;
        float s4 = red[row][0] + red[row][1] + red[row][2] + red[row][3];
        float inv = __builtin_amdgcn_rcpf(s4);
        float cval = (acc[tt][0][r] + acc[tt][1][r]) * inv;
        ctxg[row * 64 + wave * 16 + l16] = f2bf(cval);
      }
    __syncthreads();                             // B2: Plds/red free for next head
  }

  float* ap_out = attn_post + (size_t)b * 1048576 + (size_t)t0 * 1024;
#pragma unroll
  for (int tt = 0; tt < 2; ++tt)
    for (int tile = 0; tile < 16; ++tile)
      for (int r = 0; r < 4; ++r)
        ap_out[(tt * 16 + quad * 4 + r) * 1024 + sbase + tile * 16 + l16] =
            sig[tt][tile][r] * 0.0625f;
}

extern "C" void kernel_launch(void* const* d_in, const int* in_sizes, int n_in,
                              void* d_out, int out_size, void* d_ws, size_t ws_size,
                              hipStream_t stream) {
  const float* query = (const float*)d_in[0];
  const float* key   = (const float*)d_in[1];
  const float* value = (const float*)d_in[2];
  const float* Wq = (const float*)d_in[3]; const float* bq = (const float*)d_in[4];
  const float* Wk = (const float*)d_in[5]; const float* bk = (const float*)d_in[6];
  const float* Wv = (const float*)d_in[7]; const float* bv = (const float*)d_in[8];
  const float* Wo = (const float*)d_in[9]; const float* bo = (const float*)d_in[10];

  float* out0 = (float*)d_out;              // [8,1024,1024] fp32
  float* attn_post = out0 + (8u << 20);     // [8,1024,1024] fp32

  // common workspace head: 4 x 1M weightT + 3 x 8M (Qp,Kp,VpT)
  short* WqT = (short*)d_ws;
  short* WkT = WqT + (1u << 20);
  short* WvT = WkT + (1u << 20);
  short* WoT = WvT + (1u << 20);
  short* Qp  = WoT + (1u << 20);
  short* Kp  = Qp + (8u << 20);
  short* VpT = Kp + (8u << 20);

  dim3 blk(256);
  dim3 ggrid(64, 8);                        // 512 blocks, 128x128 tiles
  const size_t NEED_BIG = (size_t)(60u << 20) * 2;   // 120 MiB

  convt4<<<dim3(16, 16, 4), blk, 0, stream>>>(
      Ptr4{{Wq, Wk, Wv, Wo}, {WqT, WkT, WvT, WoT}});

  short* ctx;
  if (ws_size >= NEED_BIG) {
    // big layout: + Xq,Xk,Xv (3 x 8M) + Vflat (8M) = 60M shorts total
    short* Xq = VpT + (8u << 20);
    short* Xk = Xq + (8u << 20);
    short* Xv = Xk + (8u << 20);
    short* Vflat = Xv + (8u << 20);
    ctx = Xq;                                      // dead after qkv GEMM

    cvt3<<<dim3(4096, 1, 3), blk, 0, stream>>>(Ptr3{{query, key, value}, {Xq, Xk, Xv}});
    gemm_qkv<<<dim3(64, 8, 3), blk, 0, stream>>>(
        QkvArgs{{Xq, Xk, Xv}, {WqT, WkT, WvT}, {bq, bk, bv}, {Qp, Kp, Vflat}});
    transp_v<<<dim3(16, 128), blk, 0, stream>>>(Vflat, VpT);
  } else {
    // small layout (88 MB, proven): Xin (8M) + Vflat (8M), sequential
    short* Xin = VpT + (8u << 20);
    short* Vflat = Xin + (8u << 20);
    ctx = Xin;

    cvt3<<<dim3(4096, 1, 1), blk, 0, stream>>>(Ptr3{{query, query, query}, {Xin, Xin, Xin}});
    gemm_bt16<<<ggrid, blk, 0, stream>>>(Xin, WqT, bq, Qp, 0);
    cvt3<<<dim3(4096, 1, 1), blk, 0, stream>>>(Ptr3{{key, key, key}, {Xin, Xin, Xin}});
    gemm_bt16<<<ggrid, blk, 0, stream>>>(Xin, WkT, bk, Kp, 0);
    cvt3<<<dim3(4096, 1, 1), blk, 0, stream>>>(Ptr3{{value, value, value}, {Xin, Xin, Xin}});
    gemm_bt16<<<ggrid, blk, 0, stream>>>(Xin, WvT, bv, Vflat, 0);
    transp_v<<<dim3(16, 128), blk, 0, stream>>>(Vflat, VpT);
  }

  attn_fused8<<<dim3(256), blk, 0, stream>>>(Qp, Kp, VpT, ctx, attn_post);
  gemm_bt16<<<ggrid, blk, 0, stream>>>(ctx, WoT, bo, out0, 2);
}